// Round 5
// baseline (261.461 us; speedup 1.0000x reference)
//
#include <hip/hip_runtime.h>
#include <hip/hip_bf16.h>

#define N_NODES 50000
#define N_EDGES 600000
#define DIM_H   128
#define NPAD    50048   // N_NODES rounded up to 128 (DMA-safe zero tail)
#define NB_SCAN 196     // ceil(N_NODES / 256)

typedef __attribute__((ext_vector_type(8))) short bf16x8;   // 8 bf16 = 4 VGPRs
typedef __attribute__((ext_vector_type(4))) float f32x4;    // MFMA acc
typedef __attribute__((ext_vector_type(4))) short short4v;

__device__ __forceinline__ short f2bs(float f) {
    __hip_bfloat16 h = __float2bfloat16(f);   // RNE
    return *reinterpret_cast<short*>(&h);
}
__device__ __forceinline__ float bs2f(short s) {
    unsigned u = ((unsigned)(unsigned short)s) << 16;
    return __builtin_bit_cast(float, u);
}
__device__ __forceinline__ float sigm(float x) { return 1.f / (1.f + __expf(-x)); }
__device__ __forceinline__ float tanh_f(float x) {
    return 2.f / (1.f + __expf(-2.f * x)) - 1.f;   // saturates correctly
}
__device__ __forceinline__ unsigned pk2(float a, float b) {
    return ((unsigned)(unsigned short)f2bs(b) << 16) | (unsigned)(unsigned short)f2bs(a);
}
__device__ __forceinline__ float unlo(unsigned u) { return bs2f((short)(u & 0xffffu)); }
__device__ __forceinline__ float unhi(unsigned u) { return bs2f((short)(u >> 16)); }

// global -> LDS async DMA, 16 B per lane; LDS dst is wave-uniform base + lane*16.
__device__ __forceinline__ void dma16(const void* g, const void* lds_uniform) {
    __builtin_amdgcn_global_load_lds(
        (const __attribute__((address_space(1))) void*)g,
        (__attribute__((address_space(3))) void*)(unsigned)(unsigned long long)lds_uniform,
        16, 0, 0);
}

// ---------------------------------------------------------------------------
// K0: prep — weight bf16 conversion + zero cnt/colsum/padded-tails
// ---------------------------------------------------------------------------
__global__ __launch_bounds__(256) void prep_k(const float* __restrict__ wmsg,
                                              const float* __restrict__ wih,
                                              const float* __restrict__ whh,
                                              short* __restrict__ wmsgB,
                                              short* __restrict__ wihB,
                                              short* __restrict__ whhB,
                                              int* __restrict__ cnt,
                                              float* __restrict__ colsum,
                                              short* __restrict__ aggTail,
                                              short* __restrict__ nodesTail) {
    int i = blockIdx.x * 256 + threadIdx.x;
    if (i < 16384) wmsgB[i] = f2bs(wmsg[i]);
    if (i < 49152) { wihB[i] = f2bs(wih[i]); whhB[i] = f2bs(whh[i]); }
    if (i < N_NODES) cnt[i] = 0;
    if (i < 128) colsum[i] = 0.f;
    if (i < 1536) {           // 48 rows x 128 shorts = 6144 shorts = 1536 short4
        short4v z = {0, 0, 0, 0};
        *(short4v*)(aggTail   + i * 4) = z;
        *(short4v*)(nodesTail + i * 4) = z;
    }
}

// ---------------------------------------------------------------------------
// K1: column sums of nodes + bf16 copy of nodes
// ---------------------------------------------------------------------------
__global__ __launch_bounds__(256) void colsum_k(const float* __restrict__ nodes,
                                                float* __restrict__ colsum,
                                                short* __restrict__ nodesB) {
    __shared__ float red[8][128];
    const int tid = threadIdx.x;
    const int cg = tid & 31;
    const int rl = tid >> 5;
    float4 acc = {0.f, 0.f, 0.f, 0.f};
    for (int r = blockIdx.x * 8 + rl; r < N_NODES; r += gridDim.x * 8) {
        float4 v = *(const float4*)(nodes + (size_t)r * DIM_H + cg * 4);
        acc.x += v.x; acc.y += v.y; acc.z += v.z; acc.w += v.w;
        *(short4v*)(nodesB + (size_t)r * DIM_H + cg * 4) =
            (short4v){f2bs(v.x), f2bs(v.y), f2bs(v.z), f2bs(v.w)};
    }
    *(float4*)&red[rl][cg * 4] = acc;
    __syncthreads();
    if (tid < 128) {
        float s = 0.f;
#pragma unroll
        for (int i = 0; i < 8; ++i) s += red[i][tid];
        unsafeAtomicAdd(&colsum[tid], s);
    }
}

// ---------------------------------------------------------------------------
// CSR build: hist -> (bsum, scan2) -> reorder   (counting sort by dst)
// ---------------------------------------------------------------------------
__global__ __launch_bounds__(256) void hist_k(const int* __restrict__ edst,
                                              int* __restrict__ cnt) {
    int e = blockIdx.x * 256 + threadIdx.x;
    if (e < N_EDGES) atomicAdd(&cnt[edst[e]], 1);
}

__global__ __launch_bounds__(256) void bsum_k(const int* __restrict__ cnt,
                                              int* __restrict__ bsum) {
    const int t = threadIdx.x;
    int i = blockIdx.x * 256 + t;
    int v = (i < N_NODES) ? cnt[i] : 0;
#pragma unroll
    for (int o = 32; o; o >>= 1) v += __shfl_xor(v, o, 64);
    __shared__ int w4[4];
    if ((t & 63) == 0) w4[t >> 6] = v;
    __syncthreads();
    if (t == 0) bsum[blockIdx.x] = w4[0] + w4[1] + w4[2] + w4[3];
}

__global__ __launch_bounds__(256) void scan2_k(const int* __restrict__ cnt,
                                               const int* __restrict__ bsum,
                                               int* __restrict__ rowptr,
                                               int* __restrict__ pos) {
    const int b = blockIdx.x, t = threadIdx.x;
    const int lane = t & 63, w = t >> 6;
    __shared__ int red[4];
    __shared__ int wsum[4];

    int ov = (t < b) ? bsum[t] : 0;
#pragma unroll
    for (int o = 32; o; o >>= 1) ov += __shfl_xor(ov, o, 64);
    if (lane == 0) red[w] = ov;
    __syncthreads();
    const int offset = red[0] + red[1] + red[2] + red[3];

    int i = b * 256 + t;
    int v = (i < N_NODES) ? cnt[i] : 0;
    int x = v;
#pragma unroll
    for (int o = 1; o < 64; o <<= 1) {
        int y = __shfl_up(x, o, 64);
        if (lane >= o) x += y;
    }
    if (lane == 63) wsum[w] = x;
    __syncthreads();
    int woff = 0;
#pragma unroll
    for (int j = 0; j < 4; ++j)
        if (j < w) woff += wsum[j];
    int excl = offset + woff + (x - v);
    if (i < N_NODES) { rowptr[i] = excl; pos[i] = excl; }
    if (i == N_NODES - 1) rowptr[N_NODES] = excl + v;
}

__global__ __launch_bounds__(256) void reorder_k(const int* __restrict__ esrc,
                                                 const int* __restrict__ edst,
                                                 int* __restrict__ pos,
                                                 int* __restrict__ ssrc) {
    int e = blockIdx.x * 256 + threadIdx.x;
    if (e < N_EDGES) {
        int p = atomicAdd(&pos[edst[e]], 1);
        ssrc[p] = esrc[e];
    }
}

// ---------------------------------------------------------------------------
// K2: gather-aggregate  aggB[n] = bf16( sum_{e in row n} nodesB[ssrc[e]] )
// ---------------------------------------------------------------------------
__global__ __launch_bounds__(256) void aggregate_k(const short* __restrict__ nodesB,
                                                   const int* __restrict__ rowptr,
                                                   const int* __restrict__ ssrc,
                                                   short* __restrict__ aggB) {
    const int wid = threadIdx.x >> 6;
    const int lane = threadIdx.x & 63;
    const int n = blockIdx.x * 4 + wid;
    if (n >= N_NODES) return;
    const int s0 = rowptr[n], s1 = rowptr[n + 1];
    float2 acc = {0.f, 0.f};
    int e = s0;
    for (; e + 3 < s1; e += 4) {
        int sa = ssrc[e], sb = ssrc[e + 1], sc = ssrc[e + 2], sd = ssrc[e + 3];
        short2 va = ((const short2*)(nodesB + (size_t)sa * DIM_H))[lane];
        short2 vb = ((const short2*)(nodesB + (size_t)sb * DIM_H))[lane];
        short2 vc = ((const short2*)(nodesB + (size_t)sc * DIM_H))[lane];
        short2 vd = ((const short2*)(nodesB + (size_t)sd * DIM_H))[lane];
        acc.x += (bs2f(va.x) + bs2f(vb.x)) + (bs2f(vc.x) + bs2f(vd.x));
        acc.y += (bs2f(va.y) + bs2f(vb.y)) + (bs2f(vc.y) + bs2f(vd.y));
    }
    for (; e < s1; ++e) {
        int sa = ssrc[e];
        short2 va = ((const short2*)(nodesB + (size_t)sa * DIM_H))[lane];
        acc.x += bs2f(va.x);
        acc.y += bs2f(va.y);
    }
    short2 o; o.x = f2bs(acc.x); o.y = f2bs(acc.y);
    ((short2*)(aggB + (size_t)n * DIM_H))[lane] = o;
}

// ---------------------------------------------------------------------------
// K3: FULLY FUSED, wave-local, depth-2 counted-vmcnt pipeline.
// Wave w owns output rows [w*16, w*16+16) for all 7 GEMM passes; A operands
// (agg/nodes/msgin) live in registers. Weights stream through THREE 16 KB LDS
// buffers with depth-2 prefetch: phase k = { s_waitcnt vmcnt(4); s_barrier;
// STAGE(k+2); MFMA chunk k }. The counted wait keeps stage(k+1) in flight
// ACROSS the barrier (never drains to 0 in the loop), so each stage has two
// full phases of compute to hide under — the round-4 __syncthreads()
// vmcnt(0)-drain was the serializer. LDS = 69 KB -> 2 blocks/CU, giving a
// 256-VGPR/wave budget (no spill risk for the h-prefetch regs).
// ---------------------------------------------------------------------------
__global__ __launch_bounds__(256) void fused_k(const short* __restrict__ aggB,
                                               const short* __restrict__ nodesB,
                                               const short* __restrict__ wmsgB,
                                               const short* __restrict__ wihB,
                                               const short* __restrict__ whhB,
                                               const float* __restrict__ bmsg,
                                               const float* __restrict__ bih,
                                               const float* __restrict__ bhh,
                                               const int* __restrict__ deg,
                                               const float* __restrict__ colsum,
                                               const float* __restrict__ gamma,
                                               const float* __restrict__ beta,
                                               float* __restrict__ out) {
    __shared__ short Ms[64 * 128];        // msgin tile (wave-local rows)  16 KB
    __shared__ short Wb[3][64 * 128];     // triple-buffered weight chunks 48 KB
    __shared__ float biasL[1280];         // bih|bhh|bmsg|cs|gamma|beta     5 KB

    const int tid = threadIdx.x;
    const int lane = tid & 63, w = tid >> 6;
    const int m0 = blockIdx.x * 64;
    const int r16 = lane & 15, qh = lane >> 4;      // lane = 16*qh + r16
    const int wm = w * 16;                           // wave's 16-row strip
    const float invN = 1.0f / N_NODES;

    // ---- prologue A: biases -> LDS ----
    for (int i = tid; i < 384; i += 256) {
        biasL[i]       = bih[i];
        biasL[384 + i] = bhh[i];
    }
    if (tid < 128) {
        biasL[768  + tid] = bmsg[tid];
        biasL[896  + tid] = colsum[tid] * invN;
        biasL[1024 + tid] = gamma[tid];
        biasL[1152 + tid] = beta[tid];
    }

    // ---- prologue B: A-fragments (regs) + deg + stage chunks 0,1 ----
    bf16x8 aggF[4], nodF[4], msgF[4];
    const size_t rowA = (size_t)(m0 + wm + r16) * 128;
#pragma unroll
    for (int kt = 0; kt < 4; ++kt) {
        aggF[kt] = *(const bf16x8*)(aggB   + rowA + ((kt << 2) + qh) * 8);
        nodF[kt] = *(const bf16x8*)(nodesB + rowA + ((kt << 2) + qh) * 8);
    }
    int4 dgi = *(const int4*)(deg + m0 + wm + qh * 4);

    // weight chunk staging: 64 rows x 128 cols, XOR-swizzled 16B granules.
#define STAGE_W(SRC, ROW0, BUF) do {                                         \
    _Pragma("unroll") for (int it = 0; it < 4; ++it) {                       \
        int c = w * 4 + it;                                                  \
        int s = c * 64 + lane;                                               \
        int r = s >> 4, q = s & 15;                                          \
        int g = q ^ (r & 15);                                                \
        dma16((SRC) + (((size_t)((ROW0) + r)) << 7) + (g << 3),              \
              &Wb[BUF][0] + (size_t)c * 512);                                \
    } } while (0)

    STAGE_W(wmsgB,  0, 0);                // chunk 0
    STAGE_W(wmsgB, 64, 1);                // chunk 1
    __syncthreads();                      // full drain once (prologue only)

    // counted-vmcnt phase barrier: wait own stage (leave N newest in flight),
    // fence the scheduler, rendezvous. Wait BEFORE barrier so every wave's
    // stage-k is complete when any wave proceeds.
#define PBAR(NLIT) do {                                                      \
    asm volatile("s_waitcnt vmcnt(" #NLIT ")" ::: "memory");                 \
    __builtin_amdgcn_sched_barrier(0);                                       \
    __builtin_amdgcn_s_barrier();                                            \
    __builtin_amdgcn_sched_barrier(0);                                       \
    } while (0)

    f32x4 acc[2][4];
    unsigned rp[2][4][2], inp[2][4][2], np_[2][4][2];

#define CHUNK(BUF, AF, H, RST) do {                                          \
    _Pragma("unroll") for (int kt = 0; kt < 4; ++kt) {                       \
        const int sq = (((kt << 2) + qh) ^ r16) << 3;                        \
        bf16x8 b0 = *(const bf16x8*)&Wb[BUF][(r16     ) * 128 + sq];         \
        bf16x8 b1 = *(const bf16x8*)&Wb[BUF][(r16 + 16) * 128 + sq];         \
        bf16x8 b2 = *(const bf16x8*)&Wb[BUF][(r16 + 32) * 128 + sq];         \
        bf16x8 b3 = *(const bf16x8*)&Wb[BUF][(r16 + 48) * 128 + sq];         \
        f32x4 z4 = {0.f, 0.f, 0.f, 0.f};                                     \
        acc[H][0] = __builtin_amdgcn_mfma_f32_16x16x32_bf16(                 \
            AF[kt], b0, ((RST) && kt == 0) ? z4 : acc[H][0], 0, 0, 0);       \
        acc[H][1] = __builtin_amdgcn_mfma_f32_16x16x32_bf16(                 \
            AF[kt], b1, ((RST) && kt == 0) ? z4 : acc[H][1], 0, 0, 0);       \
        acc[H][2] = __builtin_amdgcn_mfma_f32_16x16x32_bf16(                 \
            AF[kt], b2, ((RST) && kt == 0) ? z4 : acc[H][2], 0, 0, 0);       \
        acc[H][3] = __builtin_amdgcn_mfma_f32_16x16x32_bf16(                 \
            AF[kt], b3, ((RST) && kt == 0) ? z4 : acc[H][3], 0, 0, 0);       \
    } } while (0)

    // -------- phase 0 (prologue already synced; both c0,c1 resident) --------
    STAGE_W(wihB,   0, 2);  CHUNK(0, aggF, 0, 1);                 // c0
    // -------- phase 1 --------
    PBAR(4); STAGE_W(wihB,  64, 0);  CHUNK(1, aggF, 1, 1);        // c1
    // EPI1: msgin = acc + deg*bmsg + colsum/N -> bf16 -> Ms, read back msgF
    {
        float dgf[4];
        dgf[0] = (m0 + wm + qh * 4 + 0 < N_NODES) ? (float)dgi.x : 0.f;
        dgf[1] = (m0 + wm + qh * 4 + 1 < N_NODES) ? (float)dgi.y : 0.f;
        dgf[2] = (m0 + wm + qh * 4 + 2 < N_NODES) ? (float)dgi.z : 0.f;
        dgf[3] = (m0 + wm + qh * 4 + 3 < N_NODES) ? (float)dgi.w : 0.f;
#pragma unroll
        for (int h = 0; h < 2; ++h)
#pragma unroll
            for (int j = 0; j < 4; ++j) {
                int c = h * 64 + j * 16 + r16;
                float bm = biasL[768 + c], cs = biasL[896 + c];
#pragma unroll
                for (int rr = 0; rr < 4; ++rr) {
                    int lr = wm + qh * 4 + rr;
                    float v = acc[h][j][rr] + dgf[rr] * bm + cs;
                    int slot = (c >> 3) ^ (lr & 15);
                    Ms[lr * 128 + slot * 8 + (c & 7)] = f2bs(v);
                }
            }
#pragma unroll
        for (int kt = 0; kt < 4; ++kt) {
            int kg = (kt << 2) + qh;
            msgF[kt] = *(const bf16x8*)&Ms[(wm + r16) * 128 + ((kg ^ r16) << 3)];
        }
    }
    // -------- phases 2..5 (r gate) --------
    PBAR(4); STAGE_W(whhB,   0, 1);  CHUNK(2, msgF, 0, 1);        // c2
    PBAR(4); STAGE_W(whhB,  64, 2);  CHUNK(0, msgF, 1, 1);        // c3
    PBAR(4); STAGE_W(wihB, 256, 0);  CHUNK(1, nodF, 0, 0);        // c4
    PBAR(4); STAGE_W(wihB, 320, 1);  CHUNK(2, nodF, 1, 0);        // c5
    // EPI2: r gate
#pragma unroll
    for (int h = 0; h < 2; ++h)
#pragma unroll
        for (int j = 0; j < 4; ++j) {
            int c = h * 64 + j * 16 + r16;
            float b0 = biasL[c] + biasL[384 + c];
            rp[h][j][0] = pk2(sigm(acc[h][j][0] + b0), sigm(acc[h][j][1] + b0));
            rp[h][j][1] = pk2(sigm(acc[h][j][2] + b0), sigm(acc[h][j][3] + b0));
        }
    // -------- phases 6..7 (i_n) --------
    PBAR(4); STAGE_W(whhB, 256, 2);  CHUNK(0, msgF, 0, 1);        // c6
    PBAR(4); STAGE_W(whhB, 320, 0);  CHUNK(1, msgF, 1, 1);        // c7
    // EPI3: i_n
#pragma unroll
    for (int h = 0; h < 2; ++h)
#pragma unroll
        for (int j = 0; j < 4; ++j) {
            int c = h * 64 + j * 16 + r16;
            float bi = biasL[256 + c];
            inp[h][j][0] = pk2(acc[h][j][0] + bi, acc[h][j][1] + bi);
            inp[h][j][1] = pk2(acc[h][j][2] + bi, acc[h][j][3] + bi);
        }
    // -------- phases 8..9 (h_n, then n) --------
    PBAR(4); STAGE_W(wihB, 128, 1);  CHUNK(2, nodF, 0, 1);        // c8
    PBAR(4); STAGE_W(wihB, 192, 2);  CHUNK(0, nodF, 1, 1);        // c9
    // EPI4: n = tanh(i_n + r * h_n)
#pragma unroll
    for (int h = 0; h < 2; ++h)
#pragma unroll
        for (int j = 0; j < 4; ++j) {
            int c = h * 64 + j * 16 + r16;
            float bh = biasL[640 + c];
            float n0 = tanh_f(unlo(inp[h][j][0]) + unlo(rp[h][j][0]) * (acc[h][j][0] + bh));
            float n1 = tanh_f(unhi(inp[h][j][0]) + unhi(rp[h][j][0]) * (acc[h][j][1] + bh));
            float n2 = tanh_f(unlo(inp[h][j][1]) + unlo(rp[h][j][1]) * (acc[h][j][2] + bh));
            float n3 = tanh_f(unhi(inp[h][j][1]) + unhi(rp[h][j][1]) * (acc[h][j][3] + bh));
            np_[h][j][0] = pk2(n0, n1);
            np_[h][j][1] = pk2(n2, n3);
        }
    // -------- phases 10..13 (z gate) --------
    PBAR(4); STAGE_W(whhB, 128, 0);  CHUNK(1, msgF, 0, 1);        // c10
    PBAR(4); STAGE_W(whhB, 192, 1);  CHUNK(2, msgF, 1, 1);        // c11
    PBAR(4);                         CHUNK(0, nodF, 0, 0);        // c12
    // prefetch h (bf16 nodes) for EPI5; stays in flight across the next PBAR
    short hs[2][4][4];
#pragma unroll
    for (int h = 0; h < 2; ++h)
#pragma unroll
        for (int j = 0; j < 4; ++j)
#pragma unroll
            for (int rr = 0; rr < 4; ++rr) {
                int lr = wm + qh * 4 + rr;
                int c = h * 64 + j * 16 + r16;
                hs[h][j][rr] = nodesB[(size_t)(m0 + lr) * 128 + c];
            }
    PBAR(32);                        CHUNK(1, nodF, 1, 0);        // c13
    // EPI5: z; h' = (1-z)*n + z*h
#pragma unroll
    for (int h = 0; h < 2; ++h)
#pragma unroll
        for (int j = 0; j < 4; ++j) {
            int c = h * 64 + j * 16 + r16;
            float b1 = biasL[128 + c] + biasL[512 + c];
#pragma unroll
            for (int rr = 0; rr < 4; ++rr) {
                float hv = bs2f(hs[h][j][rr]);
                float z = sigm(acc[h][j][rr] + b1);
                float nv = (rr & 1) ? unhi(np_[h][j][rr >> 1]) : unlo(np_[h][j][rr >> 1]);
                acc[h][j][rr] = (1.f - z) * nv + z * hv;   // acc := h_next
            }
        }

    // ---- LayerNorm (wave-local: each row lives in one 16-lane group) ----
#pragma unroll
    for (int rr = 0; rr < 4; ++rr) {
        float s = 0.f, q2 = 0.f;
#pragma unroll
        for (int h = 0; h < 2; ++h)
#pragma unroll
            for (int j = 0; j < 4; ++j) {
                float v = acc[h][j][rr];
                s += v; q2 += v * v;
            }
#pragma unroll
        for (int o = 1; o < 16; o <<= 1) {
            s  += __shfl_xor(s, o, 64);
            q2 += __shfl_xor(q2, o, 64);
        }
        int lr = wm + qh * 4 + rr;
        int gm = m0 + lr;
        float mu = s * (1.0f / DIM_H);
        float var = q2 * (1.0f / DIM_H) - mu * mu;
        float rstd = rsqrtf(var + 1e-5f);
        if (gm < N_NODES) {
#pragma unroll
            for (int h = 0; h < 2; ++h)
#pragma unroll
                for (int j = 0; j < 4; ++j) {
                    int c = h * 64 + j * 16 + r16;
                    int slot = (c >> 3) ^ (lr & 15);
                    float resid = bs2f(Ms[lr * 128 + slot * 8 + (c & 7)])
                                - biasL[896 + c];
                    out[(size_t)gm * DIM_H + c] =
                        biasL[1024 + c] * (acc[h][j][rr] - mu) * rstd
                        + biasL[1152 + c] + resid;
                }
        }
    }
#undef CHUNK
#undef PBAR
#undef STAGE_W
}

// ---------------------------------------------------------------------------
extern "C" void kernel_launch(void* const* d_in, const int* in_sizes, int n_in,
                              void* d_out, int out_size, void* d_ws, size_t ws_size,
                              hipStream_t stream) {
    const float* nodes = (const float*)d_in[0];
    const float* Wmsg  = (const float*)d_in[1];
    const float* bmsg  = (const float*)d_in[2];
    const float* wih   = (const float*)d_in[3];
    const float* whh   = (const float*)d_in[4];
    const float* bih   = (const float*)d_in[5];
    const float* bhh   = (const float*)d_in[6];
    const float* gamma = (const float*)d_in[7];
    const float* beta  = (const float*)d_in[8];
    const int* esrc = (const int*)d_in[9];
    const int* edst = (const int*)d_in[10];
    float* out = (float*)d_out;

    // workspace layout (~29 MB)
    char* ws = (char*)d_ws;
    short* aggB   = (short*)ws;                        // NPAD*256 B = 12,812,288
    short* nodesB = (short*)(ws + 12812288);           // 12,812,288
    short* wmsgB  = (short*)(ws + 25624576);           // 32 KB
    short* wihB   = (short*)(ws + 25657344);           // 96 KB
    short* whhB   = (short*)(ws + 25755648);           // 96 KB
    float* colsum = (float*)(ws + 25853952);           // 512 B
    int*   cnt    = (int*)(ws + 25854464);             // 200 KB (degree after hist)
    int*   rowptr = (int*)(ws + 26054464);             // 200 KB + pad
    int*   pos    = (int*)(ws + 26254480);             // 200 KB
    int*   ssrc   = (int*)(ws + 26454480);             // 2.4 MB
    int*   bsum   = (int*)(ws + 28854480);             // 784 B -> end ~28.9 MB

    short* aggTail   = aggB   + (size_t)N_NODES * DIM_H;
    short* nodesTail = nodesB + (size_t)N_NODES * DIM_H;

    prep_k<<<NB_SCAN, 256, 0, stream>>>(Wmsg, wih, whh, wmsgB, wihB, whhB,
                                        cnt, colsum, aggTail, nodesTail);
    colsum_k<<<512, 256, 0, stream>>>(nodes, colsum, nodesB);

    const int EB = (N_EDGES + 255) / 256;
    hist_k<<<EB, 256, 0, stream>>>(edst, cnt);
    bsum_k<<<NB_SCAN, 256, 0, stream>>>(cnt, bsum);
    scan2_k<<<NB_SCAN, 256, 0, stream>>>(cnt, bsum, rowptr, pos);
    reorder_k<<<EB, 256, 0, stream>>>(esrc, edst, pos, ssrc);
    aggregate_k<<<(N_NODES + 3) / 4, 256, 0, stream>>>(nodesB, rowptr, ssrc, aggB);

    const int MB = (N_NODES + 63) / 64;   // 782
    fused_k<<<MB, 256, 0, stream>>>(aggB, nodesB, wmsgB, wihB, whhB,
                                    bmsg, bih, bhh, cnt, colsum, gamma, beta, out);
}

// Round 6
// 236.155 us; speedup vs baseline: 1.1072x; 1.1072x over previous
//
#include <hip/hip_runtime.h>
#include <hip/hip_bf16.h>

#define N_NODES 50000
#define N_EDGES 600000
#define DIM_H   128
#define NPAD    50048   // N_NODES rounded up to 128 (DMA-safe zero tail)
#define NB_SCAN 196     // ceil(N_NODES / 256)

typedef __attribute__((ext_vector_type(8))) short bf16x8;   // 8 bf16 = 4 VGPRs
typedef __attribute__((ext_vector_type(4))) float f32x4;    // MFMA acc
typedef __attribute__((ext_vector_type(4))) short short4v;

__device__ __forceinline__ short f2bs(float f) {
    __hip_bfloat16 h = __float2bfloat16(f);   // RNE
    return *reinterpret_cast<short*>(&h);
}
__device__ __forceinline__ float bs2f(short s) {
    unsigned u = ((unsigned)(unsigned short)s) << 16;
    return __builtin_bit_cast(float, u);
}
__device__ __forceinline__ float sigm(float x) { return 1.f / (1.f + __expf(-x)); }
__device__ __forceinline__ float tanh_f(float x) {
    return 2.f / (1.f + __expf(-2.f * x)) - 1.f;   // saturates correctly
}
__device__ __forceinline__ unsigned pk2(float a, float b) {
    return ((unsigned)(unsigned short)f2bs(b) << 16) | (unsigned)(unsigned short)f2bs(a);
}
__device__ __forceinline__ float unlo(unsigned u) { return bs2f((short)(u & 0xffffu)); }
__device__ __forceinline__ float unhi(unsigned u) { return bs2f((short)(u >> 16)); }

// global -> LDS async DMA, 16 B per lane; LDS dst is wave-uniform base + lane*16.
__device__ __forceinline__ void dma16(const void* g, const void* lds_uniform) {
    __builtin_amdgcn_global_load_lds(
        (const __attribute__((address_space(1))) void*)g,
        (__attribute__((address_space(3))) void*)(unsigned)(unsigned long long)lds_uniform,
        16, 0, 0);
}

// ---------------------------------------------------------------------------
// K0: prep — weight bf16 conversion + zero cnt/colsum/padded-tails
// ---------------------------------------------------------------------------
__global__ __launch_bounds__(256) void prep_k(const float* __restrict__ wmsg,
                                              const float* __restrict__ wih,
                                              const float* __restrict__ whh,
                                              short* __restrict__ wmsgB,
                                              short* __restrict__ wihB,
                                              short* __restrict__ whhB,
                                              int* __restrict__ cnt,
                                              float* __restrict__ colsum,
                                              short* __restrict__ aggTail,
                                              short* __restrict__ nodesTail) {
    int i = blockIdx.x * 256 + threadIdx.x;
    if (i < 16384) wmsgB[i] = f2bs(wmsg[i]);
    if (i < 49152) { wihB[i] = f2bs(wih[i]); whhB[i] = f2bs(whh[i]); }
    if (i < N_NODES) cnt[i] = 0;
    if (i < 128) colsum[i] = 0.f;
    if (i < 1536) {           // 48 rows x 128 shorts = 6144 shorts = 1536 short4
        short4v z = {0, 0, 0, 0};
        *(short4v*)(aggTail   + i * 4) = z;
        *(short4v*)(nodesTail + i * 4) = z;
    }
}

// ---------------------------------------------------------------------------
// K1: column sums of nodes + bf16 copy of nodes
// ---------------------------------------------------------------------------
__global__ __launch_bounds__(256) void colsum_k(const float* __restrict__ nodes,
                                                float* __restrict__ colsum,
                                                short* __restrict__ nodesB) {
    __shared__ float red[8][128];
    const int tid = threadIdx.x;
    const int cg = tid & 31;
    const int rl = tid >> 5;
    float4 acc = {0.f, 0.f, 0.f, 0.f};
    for (int r = blockIdx.x * 8 + rl; r < N_NODES; r += gridDim.x * 8) {
        float4 v = *(const float4*)(nodes + (size_t)r * DIM_H + cg * 4);
        acc.x += v.x; acc.y += v.y; acc.z += v.z; acc.w += v.w;
        *(short4v*)(nodesB + (size_t)r * DIM_H + cg * 4) =
            (short4v){f2bs(v.x), f2bs(v.y), f2bs(v.z), f2bs(v.w)};
    }
    *(float4*)&red[rl][cg * 4] = acc;
    __syncthreads();
    if (tid < 128) {
        float s = 0.f;
#pragma unroll
        for (int i = 0; i < 8; ++i) s += red[i][tid];
        unsafeAtomicAdd(&colsum[tid], s);
    }
}

// ---------------------------------------------------------------------------
// CSR build: hist -> (bsum, scan2) -> reorder   (counting sort by dst)
// 4 edges/thread, int4 loads.
// ---------------------------------------------------------------------------
__global__ __launch_bounds__(256) void hist_k(const int* __restrict__ edst,
                                              int* __restrict__ cnt) {
    int e = (blockIdx.x * 256 + threadIdx.x) * 4;
    if (e + 3 < N_EDGES) {
        int4 d = *(const int4*)(edst + e);
        atomicAdd(&cnt[d.x], 1); atomicAdd(&cnt[d.y], 1);
        atomicAdd(&cnt[d.z], 1); atomicAdd(&cnt[d.w], 1);
    } else {
        for (; e < N_EDGES; ++e) atomicAdd(&cnt[edst[e]], 1);
    }
}

__global__ __launch_bounds__(256) void bsum_k(const int* __restrict__ cnt,
                                              int* __restrict__ bsum) {
    const int t = threadIdx.x;
    int i = blockIdx.x * 256 + t;
    int v = (i < N_NODES) ? cnt[i] : 0;
#pragma unroll
    for (int o = 32; o; o >>= 1) v += __shfl_xor(v, o, 64);
    __shared__ int w4[4];
    if ((t & 63) == 0) w4[t >> 6] = v;
    __syncthreads();
    if (t == 0) bsum[blockIdx.x] = w4[0] + w4[1] + w4[2] + w4[3];
}

__global__ __launch_bounds__(256) void scan2_k(const int* __restrict__ cnt,
                                               const int* __restrict__ bsum,
                                               int* __restrict__ rowptr,
                                               int* __restrict__ pos) {
    const int b = blockIdx.x, t = threadIdx.x;
    const int lane = t & 63, w = t >> 6;
    __shared__ int red[4];
    __shared__ int wsum[4];

    int ov = (t < b) ? bsum[t] : 0;
#pragma unroll
    for (int o = 32; o; o >>= 1) ov += __shfl_xor(ov, o, 64);
    if (lane == 0) red[w] = ov;
    __syncthreads();
    const int offset = red[0] + red[1] + red[2] + red[3];

    int i = b * 256 + t;
    int v = (i < N_NODES) ? cnt[i] : 0;
    int x = v;
#pragma unroll
    for (int o = 1; o < 64; o <<= 1) {
        int y = __shfl_up(x, o, 64);
        if (lane >= o) x += y;
    }
    if (lane == 63) wsum[w] = x;
    __syncthreads();
    int woff = 0;
#pragma unroll
    for (int j = 0; j < 4; ++j)
        if (j < w) woff += wsum[j];
    int excl = offset + woff + (x - v);
    if (i < N_NODES) { rowptr[i] = excl; pos[i] = excl; }
    if (i == N_NODES - 1) rowptr[N_NODES] = excl + v;
}

__global__ __launch_bounds__(256) void reorder_k(const int* __restrict__ esrc,
                                                 const int* __restrict__ edst,
                                                 int* __restrict__ pos,
                                                 int* __restrict__ ssrc) {
    int e = (blockIdx.x * 256 + threadIdx.x) * 4;
    if (e + 3 < N_EDGES) {
        int4 s = *(const int4*)(esrc + e);
        int4 d = *(const int4*)(edst + e);
        ssrc[atomicAdd(&pos[d.x], 1)] = s.x;
        ssrc[atomicAdd(&pos[d.y], 1)] = s.y;
        ssrc[atomicAdd(&pos[d.z], 1)] = s.z;
        ssrc[atomicAdd(&pos[d.w], 1)] = s.w;
    } else {
        for (; e < N_EDGES; ++e) {
            int p = atomicAdd(&pos[edst[e]], 1);
            ssrc[p] = esrc[e];
        }
    }
}

// ---------------------------------------------------------------------------
// K2: gather-aggregate, wide-load edition.
// One wave per node; 16 lanes per edge-row (bf16x8 = 16 B/lane), so each
// wave-instruction gathers FOUR rows (1 KB) instead of one (256 B), and the
// unroll-2 loop keeps 8 edge-rows in flight. Cross-group reduce: 2 shfl_xor.
// Group 0 packs to bf16 and writes one 256 B row.
// ---------------------------------------------------------------------------
__global__ __launch_bounds__(256) void aggregate_k(const short* __restrict__ nodesB,
                                                   const int* __restrict__ rowptr,
                                                   const int* __restrict__ ssrc,
                                                   short* __restrict__ aggB) {
    const int wid = threadIdx.x >> 6;
    const int lane = threadIdx.x & 63;
    const int g = lane >> 4, l = lane & 15;     // group 0..3, lane-in-group
    const int n = blockIdx.x * 4 + wid;
    if (n >= N_NODES) return;
    const int s0 = rowptr[n], s1 = rowptr[n + 1];

    float accf[8] = {0.f, 0.f, 0.f, 0.f, 0.f, 0.f, 0.f, 0.f};
    int e = s0 + g;
    for (; e + 4 < s1; e += 8) {                // 2 rows in flight per group
        int sa = ssrc[e], sb = ssrc[e + 4];
        bf16x8 va = *(const bf16x8*)(nodesB + (size_t)sa * DIM_H + l * 8);
        bf16x8 vb = *(const bf16x8*)(nodesB + (size_t)sb * DIM_H + l * 8);
#pragma unroll
        for (int k = 0; k < 8; ++k) accf[k] += bs2f(va[k]) + bs2f(vb[k]);
    }
    if (e < s1) {
        int sa = ssrc[e];
        bf16x8 va = *(const bf16x8*)(nodesB + (size_t)sa * DIM_H + l * 8);
#pragma unroll
        for (int k = 0; k < 8; ++k) accf[k] += bs2f(va[k]);
    }
    // reduce the 4 groups (lanes l, l+16, l+32, l+48) into group 0
#pragma unroll
    for (int k = 0; k < 8; ++k) {
        accf[k] += __shfl_xor(accf[k], 32, 64);
        accf[k] += __shfl_xor(accf[k], 16, 64);
    }
    if (g == 0) {
        uint4 ov;
        ov.x = pk2(accf[0], accf[1]);
        ov.y = pk2(accf[2], accf[3]);
        ov.z = pk2(accf[4], accf[5]);
        ov.w = pk2(accf[6], accf[7]);
        *(uint4*)(aggB + (size_t)n * DIM_H + l * 8) = ov;
    }
}

// ---------------------------------------------------------------------------
// K3: FULLY FUSED, wave-local edition (round-4 proven version).
// Wave w owns output rows [w*16, w*16+16) for all 7 GEMM passes; A operands
// (agg/nodes/msgin) live in registers. Weights stream through a
// double-buffered 16 KB LDS chunk with depth-1 prefetch. LDS = 53 KB ->
// 3 blocks/CU. No min-wave launch bound (round-3 lesson: forces spills).
// (Round-5 lesson: counted-vmcnt + extra buffer LOSES — compiler still
// inserts vmcnt(0) before ds_reads and the LDS growth costs a resident block.)
// ---------------------------------------------------------------------------
__global__ __launch_bounds__(256) void fused_k(const short* __restrict__ aggB,
                                               const short* __restrict__ nodesB,
                                               const short* __restrict__ wmsgB,
                                               const short* __restrict__ wihB,
                                               const short* __restrict__ whhB,
                                               const float* __restrict__ bmsg,
                                               const float* __restrict__ bih,
                                               const float* __restrict__ bhh,
                                               const int* __restrict__ deg,
                                               const float* __restrict__ colsum,
                                               const float* __restrict__ gamma,
                                               const float* __restrict__ beta,
                                               float* __restrict__ out) {
    __shared__ short Ms[64 * 128];        // msgin tile (wave-local regions)
    __shared__ short Wb[2][64 * 128];     // double-buffered weight chunk
    __shared__ float biasL[1280];         // bih|bhh|bmsg|cs|gamma|beta

    const int tid = threadIdx.x;
    const int lane = tid & 63, w = tid >> 6;
    const int m0 = blockIdx.x * 64;
    const int r16 = lane & 15, qh = lane >> 4;      // lane = 16*qh + r16
    const int wm = w * 16;                           // wave's 16-row strip
    const float invN = 1.0f / N_NODES;

    // ---- prologue A: biases -> LDS ----
    for (int i = tid; i < 384; i += 256) {
        biasL[i]       = bih[i];
        biasL[384 + i] = bhh[i];
    }
    if (tid < 128) {
        biasL[768  + tid] = bmsg[tid];
        biasL[896  + tid] = colsum[tid] * invN;
        biasL[1024 + tid] = gamma[tid];
        biasL[1152 + tid] = beta[tid];
    }

    // ---- prologue B: A-fragments (regs) + deg + stage chunk 0 ----
    bf16x8 aggF[4], nodF[4], msgF[4];
    const size_t rowA = (size_t)(m0 + wm + r16) * 128;
#pragma unroll
    for (int kt = 0; kt < 4; ++kt) {
        aggF[kt] = *(const bf16x8*)(aggB   + rowA + ((kt << 2) + qh) * 8);
        nodF[kt] = *(const bf16x8*)(nodesB + rowA + ((kt << 2) + qh) * 8);
    }
    int4 dgi = *(const int4*)(deg + m0 + wm + qh * 4);

    // weight chunk staging: 64 rows x 128 cols, XOR-swizzled 16B granules.
#define STAGE_W(SRC, ROW0, BUF) do {                                         \
    _Pragma("unroll") for (int it = 0; it < 4; ++it) {                       \
        int c = w * 4 + it;                                                  \
        int s = c * 64 + lane;                                               \
        int r = s >> 4, q = s & 15;                                          \
        int g = q ^ (r & 15);                                                \
        dma16((SRC) + (((size_t)((ROW0) + r)) << 7) + (g << 3),              \
              &Wb[BUF][0] + (size_t)c * 512);                                \
    } } while (0)

    STAGE_W(wmsgB, 0, 0);                 // chunk 0

    f32x4 acc[2][4];
    unsigned rp[2][4][2], inp[2][4][2], np_[2][4][2];

#define CHUNK(BUF, AF, H, RST) do {                                          \
    _Pragma("unroll") for (int kt = 0; kt < 4; ++kt) {                       \
        const int sq = (((kt << 2) + qh) ^ r16) << 3;                        \
        bf16x8 b0 = *(const bf16x8*)&Wb[BUF][(r16     ) * 128 + sq];         \
        bf16x8 b1 = *(const bf16x8*)&Wb[BUF][(r16 + 16) * 128 + sq];         \
        bf16x8 b2 = *(const bf16x8*)&Wb[BUF][(r16 + 32) * 128 + sq];         \
        bf16x8 b3 = *(const bf16x8*)&Wb[BUF][(r16 + 48) * 128 + sq];         \
        f32x4 z4 = {0.f, 0.f, 0.f, 0.f};                                     \
        acc[H][0] = __builtin_amdgcn_mfma_f32_16x16x32_bf16(                 \
            AF[kt], b0, ((RST) && kt == 0) ? z4 : acc[H][0], 0, 0, 0);       \
        acc[H][1] = __builtin_amdgcn_mfma_f32_16x16x32_bf16(                 \
            AF[kt], b1, ((RST) && kt == 0) ? z4 : acc[H][1], 0, 0, 0);       \
        acc[H][2] = __builtin_amdgcn_mfma_f32_16x16x32_bf16(                 \
            AF[kt], b2, ((RST) && kt == 0) ? z4 : acc[H][2], 0, 0, 0);       \
        acc[H][3] = __builtin_amdgcn_mfma_f32_16x16x32_bf16(                 \
            AF[kt], b3, ((RST) && kt == 0) ? z4 : acc[H][3], 0, 0, 0);       \
    } } while (0)

    // ---------------- pipelined chunk sequence ----------------
    __syncthreads(); STAGE_W(wmsgB,  64, 1); CHUNK(0, aggF, 0, 1);   // c0
    __syncthreads(); STAGE_W(wihB,    0, 0); CHUNK(1, aggF, 1, 1);   // c1

    // EPI1: msgin = acc + deg*bmsg + colsum/N -> bf16 -> Ms, read back msgF
    {
        float dgf[4];
        dgf[0] = (m0 + wm + qh * 4 + 0 < N_NODES) ? (float)dgi.x : 0.f;
        dgf[1] = (m0 + wm + qh * 4 + 1 < N_NODES) ? (float)dgi.y : 0.f;
        dgf[2] = (m0 + wm + qh * 4 + 2 < N_NODES) ? (float)dgi.z : 0.f;
        dgf[3] = (m0 + wm + qh * 4 + 3 < N_NODES) ? (float)dgi.w : 0.f;
#pragma unroll
        for (int h = 0; h < 2; ++h)
#pragma unroll
            for (int j = 0; j < 4; ++j) {
                int c = h * 64 + j * 16 + r16;
                float bm = biasL[768 + c], cs = biasL[896 + c];
#pragma unroll
                for (int rr = 0; rr < 4; ++rr) {
                    int lr = wm + qh * 4 + rr;
                    float v = acc[h][j][rr] + dgf[rr] * bm + cs;
                    int slot = (c >> 3) ^ (lr & 15);
                    Ms[lr * 128 + slot * 8 + (c & 7)] = f2bs(v);
                }
            }
#pragma unroll
        for (int kt = 0; kt < 4; ++kt) {
            int kg = (kt << 2) + qh;
            msgF[kt] = *(const bf16x8*)&Ms[(wm + r16) * 128 + ((kg ^ r16) << 3)];
        }
    }

    __syncthreads(); STAGE_W(wihB,   64, 1); CHUNK(0, msgF, 0, 1);   // c2
    __syncthreads(); STAGE_W(whhB,    0, 0); CHUNK(1, msgF, 1, 1);   // c3
    __syncthreads(); STAGE_W(whhB,   64, 1); CHUNK(0, nodF, 0, 0);   // c4
    __syncthreads(); STAGE_W(wihB,  256, 0); CHUNK(1, nodF, 1, 0);   // c5
    // EPI2: r gate
#pragma unroll
    for (int h = 0; h < 2; ++h)
#pragma unroll
        for (int j = 0; j < 4; ++j) {
            int c = h * 64 + j * 16 + r16;
            float b0 = biasL[c] + biasL[384 + c];
            rp[h][j][0] = pk2(sigm(acc[h][j][0] + b0), sigm(acc[h][j][1] + b0));
            rp[h][j][1] = pk2(sigm(acc[h][j][2] + b0), sigm(acc[h][j][3] + b0));
        }

    __syncthreads(); STAGE_W(wihB,  320, 1); CHUNK(0, msgF, 0, 1);   // c6
    __syncthreads(); STAGE_W(whhB,  256, 0); CHUNK(1, msgF, 1, 1);   // c7
    // EPI3: i_n
#pragma unroll
    for (int h = 0; h < 2; ++h)
#pragma unroll
        for (int j = 0; j < 4; ++j) {
            int c = h * 64 + j * 16 + r16;
            float bi = biasL[256 + c];
            inp[h][j][0] = pk2(acc[h][j][0] + bi, acc[h][j][1] + bi);
            inp[h][j][1] = pk2(acc[h][j][2] + bi, acc[h][j][3] + bi);
        }

    __syncthreads(); STAGE_W(whhB,  320, 1); CHUNK(0, nodF, 0, 1);   // c8
    __syncthreads(); STAGE_W(wihB,  128, 0); CHUNK(1, nodF, 1, 1);   // c9
    // EPI4: n = tanh(i_n + r * h_n)
#pragma unroll
    for (int h = 0; h < 2; ++h)
#pragma unroll
        for (int j = 0; j < 4; ++j) {
            int c = h * 64 + j * 16 + r16;
            float bh = biasL[640 + c];
            float n0 = tanh_f(unlo(inp[h][j][0]) + unlo(rp[h][j][0]) * (acc[h][j][0] + bh));
            float n1 = tanh_f(unhi(inp[h][j][0]) + unhi(rp[h][j][0]) * (acc[h][j][1] + bh));
            float n2 = tanh_f(unlo(inp[h][j][1]) + unlo(rp[h][j][1]) * (acc[h][j][2] + bh));
            float n3 = tanh_f(unhi(inp[h][j][1]) + unhi(rp[h][j][1]) * (acc[h][j][3] + bh));
            np_[h][j][0] = pk2(n0, n1);
            np_[h][j][1] = pk2(n2, n3);
        }

    __syncthreads(); STAGE_W(wihB,  192, 1); CHUNK(0, msgF, 0, 1);   // c10
    __syncthreads(); STAGE_W(whhB,  128, 0); CHUNK(1, msgF, 1, 1);   // c11
    __syncthreads(); STAGE_W(whhB,  192, 1); CHUNK(0, nodF, 0, 0);   // c12
    __syncthreads();                         CHUNK(1, nodF, 1, 0);   // c13

    // EPI5: z; h' = (1-z)*n + z*h  (h from global bf16 nodes, L1-hot)
#pragma unroll
    for (int h = 0; h < 2; ++h)
#pragma unroll
        for (int j = 0; j < 4; ++j) {
            int c = h * 64 + j * 16 + r16;
            float b1 = biasL[128 + c] + biasL[512 + c];
#pragma unroll
            for (int rr = 0; rr < 4; ++rr) {
                int lr = wm + qh * 4 + rr;
                float hv = bs2f(nodesB[(size_t)(m0 + lr) * 128 + c]);
                float z = sigm(acc[h][j][rr] + b1);
                float nv = (rr & 1) ? unhi(np_[h][j][rr >> 1]) : unlo(np_[h][j][rr >> 1]);
                acc[h][j][rr] = (1.f - z) * nv + z * hv;   // acc := h_next
            }
        }

    // ---- LayerNorm (wave-local: each row lives in one 16-lane group) ----
#pragma unroll
    for (int rr = 0; rr < 4; ++rr) {
        float s = 0.f, q2 = 0.f;
#pragma unroll
        for (int h = 0; h < 2; ++h)
#pragma unroll
            for (int j = 0; j < 4; ++j) {
                float v = acc[h][j][rr];
                s += v; q2 += v * v;
            }
#pragma unroll
        for (int o = 1; o < 16; o <<= 1) {
            s  += __shfl_xor(s, o, 64);
            q2 += __shfl_xor(q2, o, 64);
        }
        int lr = wm + qh * 4 + rr;
        int gm = m0 + lr;
        float mu = s * (1.0f / DIM_H);
        float var = q2 * (1.0f / DIM_H) - mu * mu;
        float rstd = rsqrtf(var + 1e-5f);
        if (gm < N_NODES) {
#pragma unroll
            for (int h = 0; h < 2; ++h)
#pragma unroll
                for (int j = 0; j < 4; ++j) {
                    int c = h * 64 + j * 16 + r16;
                    int slot = (c >> 3) ^ (lr & 15);
                    float resid = bs2f(Ms[lr * 128 + slot * 8 + (c & 7)])
                                - biasL[896 + c];
                    out[(size_t)gm * DIM_H + c] =
                        biasL[1024 + c] * (acc[h][j][rr] - mu) * rstd
                        + biasL[1152 + c] + resid;
                }
        }
    }
#undef CHUNK
#undef STAGE_W
}

// ---------------------------------------------------------------------------
extern "C" void kernel_launch(void* const* d_in, const int* in_sizes, int n_in,
                              void* d_out, int out_size, void* d_ws, size_t ws_size,
                              hipStream_t stream) {
    const float* nodes = (const float*)d_in[0];
    const float* Wmsg  = (const float*)d_in[1];
    const float* bmsg  = (const float*)d_in[2];
    const float* wih   = (const float*)d_in[3];
    const float* whh   = (const float*)d_in[4];
    const float* bih   = (const float*)d_in[5];
    const float* bhh   = (const float*)d_in[6];
    const float* gamma = (const float*)d_in[7];
    const float* beta  = (const float*)d_in[8];
    const int* esrc = (const int*)d_in[9];
    const int* edst = (const int*)d_in[10];
    float* out = (float*)d_out;

    // workspace layout (~29 MB)
    char* ws = (char*)d_ws;
    short* aggB   = (short*)ws;                        // NPAD*256 B = 12,812,288
    short* nodesB = (short*)(ws + 12812288);           // 12,812,288
    short* wmsgB  = (short*)(ws + 25624576);           // 32 KB
    short* wihB   = (short*)(ws + 25657344);           // 96 KB
    short* whhB   = (short*)(ws + 25755648);           // 96 KB
    float* colsum = (float*)(ws + 25853952);           // 512 B
    int*   cnt    = (int*)(ws + 25854464);             // 200 KB (degree after hist)
    int*   rowptr = (int*)(ws + 26054464);             // 200 KB + pad
    int*   pos    = (int*)(ws + 26254480);             // 200 KB
    int*   ssrc   = (int*)(ws + 26454480);             // 2.4 MB
    int*   bsum   = (int*)(ws + 28854480);             // 784 B -> end ~28.9 MB

    short* aggTail   = aggB   + (size_t)N_NODES * DIM_H;
    short* nodesTail = nodesB + (size_t)N_NODES * DIM_H;

    prep_k<<<NB_SCAN, 256, 0, stream>>>(Wmsg, wih, whh, wmsgB, wihB, whhB,
                                        cnt, colsum, aggTail, nodesTail);
    colsum_k<<<512, 256, 0, stream>>>(nodes, colsum, nodesB);

    const int EB4 = (N_EDGES / 4 + 255) / 256;   // 586
    hist_k<<<EB4, 256, 0, stream>>>(edst, cnt);
    bsum_k<<<NB_SCAN, 256, 0, stream>>>(cnt, bsum);
    scan2_k<<<NB_SCAN, 256, 0, stream>>>(cnt, bsum, rowptr, pos);
    reorder_k<<<EB4, 256, 0, stream>>>(esrc, edst, pos, ssrc);
    aggregate_k<<<(N_NODES + 3) / 4, 256, 0, stream>>>(nodesB, rowptr, ssrc, aggB);

    const int MB = (N_NODES + 63) / 64;   // 782
    fused_k<<<MB, 256, 0, stream>>>(aggB, nodesB, wmsgB, wihB, whhB,
                                    bmsg, bih, bhh, cnt, colsum, gamma, beta, out);
}